// Round 1
// baseline (24206.207 us; speedup 1.0000x reference)
//
#include <hip/hip_runtime.h>
#include <hip/hip_bf16.h>

// SGEncoder — round 0: correct fp32 baseline with fused 2-layer MLP kernels.
// Pipeline:
//   1. memset(agg, cnt, graph stats) = 0
//   2. sign[E] = 1, sign[added_sym_edge] = -1
//   3. x[N][300]  = sum_t emb[x_tok]          (ws)
//      ea[E][300] = sign * sum_t emb[ea_tok]  (written into d_out edge region!)
//   4. edge MLP  (Fin=900, gather [x[row],x[col],ea]) -> edge_enc, in-place over ea
//   5. cnt[col] += 1
//   6. node MLP1 (Fin=600, gather [x[row],edge_enc])  -> atomicAdd into agg[col]
//   7. node MLP2 (Fin=600, gather [x, agg/max(cnt,1)]) -> x_enc into d_out[0:N*D]
//   8. per-node reduce -> per-graph sum/sumsq/count (atomics, G=128)
//   9. graph layernorm in-place on d_out[0:N*D]

constexpr int N_NODES = 100000;
constexpr int N_EDGES = 400000;
constexpr int TOKS    = 4;
constexpr int D       = 300;
constexpr int NG      = 128;
constexpr float EPSV  = 1e-5f;

// ---- workspace layout (float elements) ----
constexpr size_t AGG_OFF  = 0;                                // N*D
constexpr size_t CNT_OFF  = AGG_OFF + (size_t)N_NODES * D;    // N
constexpr size_t GSUM_OFF = CNT_OFF + N_NODES;                // G
constexpr size_t GSQ_OFF  = GSUM_OFF + NG;                    // G
constexpr size_t GCNT_OFF = GSQ_OFF + NG;                     // G
constexpr size_t SIGN_OFF = GCNT_OFF + NG;                    // E
constexpr size_t X_OFF    = SIGN_OFF + N_EDGES;               // N*D
constexpr size_t ZERO_FLOATS = SIGN_OFF;                      // [0, SIGN_OFF) zeroed

__global__ void fill_sign_k(float* sign) {
    int i = blockIdx.x * blockDim.x + threadIdx.x;
    if (i < N_EDGES) sign[i] = 1.0f;
}

__global__ void scatter_sign_k(const int* __restrict__ ase, float* sign) {
    int i = blockIdx.x * blockDim.x + threadIdx.x;
    if (i < N_EDGES / 2) sign[ase[i]] = -1.0f;
}

// out[r][d] = (sign ? sign[r] : 1) * sum_t emb[tok[r][t]][d]
__global__ void embsum_k(const int* __restrict__ tok, const float* __restrict__ emb,
                         const float* __restrict__ sign, float* out, int nrows) {
    int idx = blockIdx.x * blockDim.x + threadIdx.x;
    int total = nrows * D;
    if (idx >= total) return;
    int r = idx / D;
    int d = idx - r * D;
    const int* t = tok + r * TOKS;
    float s = emb[(size_t)t[0] * D + d] + emb[(size_t)t[1] * D + d]
            + emb[(size_t)t[2] * D + d] + emb[(size_t)t[3] * D + d];
    if (sign) s *= sign[r];
    out[idx] = s;
}

__global__ void count_col_k(const int* __restrict__ coli, float* cnt) {
    int i = blockIdx.x * blockDim.x + threadIdx.x;
    if (i < N_EDGES) atomicAdd(&cnt[coli[i]], 1.0f);
}

// Fused 2-layer MLP: out = relu(A@W1+b1)@W2+b2, A gathered on the fly.
// MODE 0: A = [x[row], x[col], ea]   (Fin=900), store to outp (== aux, in-place ok)
// MODE 1: A = [x[row], edge_enc]     (Fin=600), SCATTER: atomicAdd outp[col[e]]
// MODE 2: A = [x[n], agg[n]/cnt[n]]  (Fin=600), store to outp
template <int FIN, int MODE, bool SCATTER>
__global__ __launch_bounds__(256) void mlp_fused_k(
        const float* __restrict__ x, const float* aux,
        const int* __restrict__ rowi, const int* __restrict__ coli,
        const float* __restrict__ cnt,
        const float* __restrict__ W1, const float* __restrict__ b1,
        const float* __restrict__ W2, const float* __restrict__ b2,
        float* outp, int nrows) {
    constexpr int KT = 20;                       // divides 900, 600, 300
    __shared__ __align__(16) float As[KT][68];   // A-tile, transposed [k][m], padded
    __shared__ __align__(16) float Bs[KT][64];   // W-tile [k][j]
    __shared__ __hip_bfloat16 Hs[64][306];       // hidden (relu), bf16, padded
    __shared__ int Ridx[64];
    __shared__ int Cidx[64];
    __shared__ float Icnt[64];

    const int tid = threadIdx.x;
    const int r0  = blockIdx.x * 64;
    const int tx  = tid & 15;    // micro-tile col group: cols tx*4 .. tx*4+3
    const int ty  = tid >> 4;    // micro-tile row group: rows ty*4 .. ty*4+3

    if constexpr (MODE == 0 || MODE == 1) {
        if (tid < 64) {
            int e = r0 + tid; if (e >= nrows) e = nrows - 1;
            Ridx[tid] = rowi[e];
            Cidx[tid] = coli[e];
        }
    } else {
        if (tid < 64) {
            int e = r0 + tid; if (e >= nrows) e = nrows - 1;
            Icnt[tid] = 1.0f / fmaxf(cnt[e], 1.0f);
        }
    }
    __syncthreads();

    // ---------------- phase 1: Hs = relu(A @ W1 + b1), all 300 cols ----------
    for (int nc = 0; nc < 5; ++nc) {
        const int n0 = nc * 64;
        float acc[4][4] = {{0.f}};
        for (int k0 = 0; k0 < FIN; k0 += KT) {
            // stage A (gathered): 64x20 elems, 5 per thread
#pragma unroll
            for (int i = 0; i < 5; ++i) {
                int L = i * 256 + tid;
                int m = L / KT;
                int k = L - m * KT;
                int e = r0 + m; if (e >= nrows) e = nrows - 1;
                int kk = k0 + k;
                float v;
                if constexpr (MODE == 0) {
                    if (kk < D)          v = x[(size_t)Ridx[m] * D + kk];
                    else if (kk < 2 * D) v = x[(size_t)Cidx[m] * D + (kk - D)];
                    else                 v = aux[(size_t)e * D + (kk - 2 * D)];
                } else if constexpr (MODE == 1) {
                    if (kk < D) v = x[(size_t)Ridx[m] * D + kk];
                    else        v = aux[(size_t)e * D + (kk - D)];
                } else {
                    if (kk < D) v = x[(size_t)e * D + kk];
                    else        v = aux[(size_t)e * D + (kk - D)] * Icnt[m];
                }
                As[k][m] = v;
            }
            // stage B: W1 tile, zero-pad cols >= 300
#pragma unroll
            for (int i = 0; i < 5; ++i) {
                int L = i * 256 + tid;
                int k = L >> 6, j = L & 63;
                int jj = n0 + j;
                Bs[k][j] = (jj < D) ? W1[(size_t)(k0 + k) * D + jj] : 0.f;
            }
            __syncthreads();
#pragma unroll
            for (int k = 0; k < KT; ++k) {
                float4 a = *(const float4*)&As[k][ty * 4];
                float4 b = *(const float4*)&Bs[k][tx * 4];
                acc[0][0] += a.x * b.x; acc[0][1] += a.x * b.y; acc[0][2] += a.x * b.z; acc[0][3] += a.x * b.w;
                acc[1][0] += a.y * b.x; acc[1][1] += a.y * b.y; acc[1][2] += a.y * b.z; acc[1][3] += a.y * b.w;
                acc[2][0] += a.z * b.x; acc[2][1] += a.z * b.y; acc[2][2] += a.z * b.z; acc[2][3] += a.z * b.w;
                acc[3][0] += a.w * b.x; acc[3][1] += a.w * b.y; acc[3][2] += a.w * b.z; acc[3][3] += a.w * b.w;
            }
            __syncthreads();
        }
        // relu + bias, store hidden tile (bf16)
#pragma unroll
        for (int i = 0; i < 4; ++i) {
            int j = n0 + tx * 4 + i;
            float bb = (j < D) ? b1[j] : 0.f;
#pragma unroll
            for (int r = 0; r < 4; ++r) {
                float v = fmaxf(acc[r][i] + bb, 0.f);
                if (j < D) Hs[ty * 4 + r][j] = __float2bfloat16(v);
            }
        }
        __syncthreads();
    }

    // ---------------- phase 2: out = Hs @ W2 + b2 ----------------------------
    for (int nc = 0; nc < 5; ++nc) {
        const int n0 = nc * 64;
        float acc[4][4] = {{0.f}};
        for (int k0 = 0; k0 < D; k0 += KT) {
#pragma unroll
            for (int i = 0; i < 5; ++i) {
                int L = i * 256 + tid;
                int k = L >> 6, j = L & 63;
                int jj = n0 + j;
                Bs[k][j] = (jj < D) ? W2[(size_t)(k0 + k) * D + jj] : 0.f;
            }
            __syncthreads();
#pragma unroll
            for (int k = 0; k < KT; ++k) {
                int kk = k0 + k;
                float4 b = *(const float4*)&Bs[k][tx * 4];
                float a0 = __bfloat162float(Hs[ty * 4 + 0][kk]);
                float a1 = __bfloat162float(Hs[ty * 4 + 1][kk]);
                float a2 = __bfloat162float(Hs[ty * 4 + 2][kk]);
                float a3 = __bfloat162float(Hs[ty * 4 + 3][kk]);
                acc[0][0] += a0 * b.x; acc[0][1] += a0 * b.y; acc[0][2] += a0 * b.z; acc[0][3] += a0 * b.w;
                acc[1][0] += a1 * b.x; acc[1][1] += a1 * b.y; acc[1][2] += a1 * b.z; acc[1][3] += a1 * b.w;
                acc[2][0] += a2 * b.x; acc[2][1] += a2 * b.y; acc[2][2] += a2 * b.z; acc[2][3] += a2 * b.w;
                acc[3][0] += a3 * b.x; acc[3][1] += a3 * b.y; acc[3][2] += a3 * b.z; acc[3][3] += a3 * b.w;
            }
            __syncthreads();
        }
        // epilogue
#pragma unroll
        for (int i = 0; i < 4; ++i) {
            int j = n0 + tx * 4 + i;
            if (j >= D) continue;
            float bb = b2[j];
#pragma unroll
            for (int r = 0; r < 4; ++r) {
                int m = ty * 4 + r;
                int e = r0 + m;
                if (e >= nrows) continue;
                float v = acc[r][i] + bb;
                if constexpr (SCATTER) {
                    atomicAdd(&outp[(size_t)Cidx[m] * D + j], v);
                } else {
                    outp[(size_t)e * D + j] = v;
                }
            }
        }
    }
}

// one block per node: partial sums -> per-graph atomics
__global__ __launch_bounds__(256) void graph_stats_k(
        const float* __restrict__ xe, const int* __restrict__ batch,
        float* gsum, float* gsq, float* gcnt) {
    int n = blockIdx.x;
    int tid = threadIdx.x;
    float v = 0.f, v2 = 0.f;
    for (int d = tid; d < D; d += 256) {
        float t = xe[(size_t)n * D + d];
        v += t; v2 += t * t;
    }
    for (int off = 32; off > 0; off >>= 1) {
        v  += __shfl_down(v, off, 64);
        v2 += __shfl_down(v2, off, 64);
    }
    __shared__ float s1[4], s2[4];
    int w = tid >> 6, l = tid & 63;
    if (l == 0) { s1[w] = v; s2[w] = v2; }
    __syncthreads();
    if (tid == 0) {
        float a = s1[0] + s1[1] + s1[2] + s1[3];
        float b = s2[0] + s2[1] + s2[2] + s2[3];
        int g = batch[n];
        atomicAdd(&gsum[g], a);
        atomicAdd(&gsq[g], b);
        atomicAdd(&gcnt[g], 1.0f);
    }
}

__global__ void graph_norm_k(float* xe, const int* __restrict__ batch,
                             const float* __restrict__ gsum, const float* __restrict__ gsq,
                             const float* __restrict__ gcnt,
                             const float* __restrict__ lnw, const float* __restrict__ lnb) {
    int idx = blockIdx.x * blockDim.x + threadIdx.x;
    if (idx >= N_NODES * D) return;
    int n = idx / D;
    int d = idx - n * D;
    int g = batch[n];
    float denom = fmaxf(gcnt[g] * (float)D, 1.0f);
    float mean = gsum[g] / denom;
    float var  = gsq[g] / denom - mean * mean;
    float r = rsqrtf(var + EPSV);
    xe[idx] = (xe[idx] - mean) * r * lnw[d] + lnb[d];
}

extern "C" void kernel_launch(void* const* d_in, const int* in_sizes, int n_in,
                              void* d_out, int out_size, void* d_ws, size_t ws_size,
                              hipStream_t stream) {
    const int*   x_tok  = (const int*)d_in[0];
    const int*   ea_tok = (const int*)d_in[1];
    const int*   eidx   = (const int*)d_in[2];
    const int*   ase    = (const int*)d_in[3];
    const int*   batch  = (const int*)d_in[4];
    const float* emb    = (const float*)d_in[5];
    const float* ew1  = (const float*)d_in[6];
    const float* eb1  = (const float*)d_in[7];
    const float* ew2  = (const float*)d_in[8];
    const float* eb2  = (const float*)d_in[9];
    const float* n1w1 = (const float*)d_in[10];
    const float* n1b1 = (const float*)d_in[11];
    const float* n1w2 = (const float*)d_in[12];
    const float* n1b2 = (const float*)d_in[13];
    const float* n2w1 = (const float*)d_in[14];
    const float* n2b1 = (const float*)d_in[15];
    const float* n2w2 = (const float*)d_in[16];
    const float* n2b2 = (const float*)d_in[17];
    const float* lnw  = (const float*)d_in[18];
    const float* lnb  = (const float*)d_in[19];

    const int* rowi = eidx;             // edge_index[0]
    const int* coli = eidx + N_EDGES;   // edge_index[1]

    float* out  = (float*)d_out;
    float* xout = out;                       // [N, D] final x_out (x_enc pre-LN)
    float* eenc = out + (size_t)N_NODES * D; // [E, D] edge_enc (first holds ea)

    float* ws   = (float*)d_ws;
    float* agg  = ws + AGG_OFF;
    float* cnt  = ws + CNT_OFF;
    float* gsum = ws + GSUM_OFF;
    float* gsq  = ws + GSQ_OFF;
    float* gcnt = ws + GCNT_OFF;
    float* sign = ws + SIGN_OFF;
    float* x    = ws + X_OFF;

    // 1. zero accumulators
    hipMemsetAsync(ws, 0, ZERO_FLOATS * sizeof(float), stream);

    // 2. sign
    fill_sign_k<<<(N_EDGES + 255) / 256, 256, 0, stream>>>(sign);
    scatter_sign_k<<<(N_EDGES / 2 + 255) / 256, 256, 0, stream>>>(ase, sign);

    // 3. embedding sums
    embsum_k<<<(N_NODES * D + 255) / 256, 256, 0, stream>>>(x_tok, emb, nullptr, x, N_NODES);
    embsum_k<<<(N_EDGES * D + 255) / 256, 256, 0, stream>>>(ea_tok, emb, sign, eenc, N_EDGES);

    // 4. edge MLP (in-place over ea in d_out)
    mlp_fused_k<900, 0, false><<<N_EDGES / 64, 256, 0, stream>>>(
        x, eenc, rowi, coli, nullptr, ew1, eb1, ew2, eb2, eenc, N_EDGES);

    // 5. in-degree counts
    count_col_k<<<(N_EDGES + 255) / 256, 256, 0, stream>>>(coli, cnt);

    // 6. node MLP1 -> scatter-add into agg
    mlp_fused_k<600, 1, true><<<N_EDGES / 64, 256, 0, stream>>>(
        x, eenc, rowi, coli, nullptr, n1w1, n1b1, n1w2, n1b2, agg, N_EDGES);

    // 7. node MLP2 (agg/cnt folded into gather) -> x_enc in d_out
    mlp_fused_k<600, 2, false><<<(N_NODES + 63) / 64, 256, 0, stream>>>(
        x, agg, nullptr, nullptr, cnt, n2w1, n2b1, n2w2, n2b2, xout, N_NODES);

    // 8-9. graph layernorm
    graph_stats_k<<<N_NODES, 256, 0, stream>>>(xout, batch, gsum, gsq, gcnt);
    graph_norm_k<<<(N_NODES * D + 255) / 256, 256, 0, stream>>>(
        xout, batch, gsum, gsq, gcnt, lnw, lnb);
}